// Round 1
// baseline (149.722 us; speedup 1.0000x reference)
//
#include <hip/hip_runtime.h>

// GraphSAGE fused layer: out[B,128] = relu(concat(feat[nodes], mean_s feat[neigh])[B,256] @ W[256,128])
// B=50000, S=10, D=128, H=128. fp32 in/out; bf16 MFMA for the matmul (threshold allows bf16).

typedef __attribute__((ext_vector_type(8))) short bf16x8;   // 8 bf16 in 4 VGPRs (MFMA A/B frag)
typedef __attribute__((ext_vector_type(4))) float f32x4;    // MFMA C/D frag

#define THREADS 512
#define B_TILE 64

__device__ __forceinline__ unsigned short f2bf(float x) {
  // round-to-nearest-even fp32 -> bf16 (no NaN handling needed; inputs are finite)
  unsigned int u = __float_as_uint(x);
  u += 0x7fffu + ((u >> 16) & 1u);
  return (unsigned short)(u >> 16);
}

__global__ __launch_bounds__(THREADS, 1)
void sage_fused(const int* __restrict__ nodes,
                const int* __restrict__ neigh,
                const float* __restrict__ feat,
                const float* __restrict__ W,
                float* __restrict__ out,
                int B)
{
  constexpr int D = 128, K = 256, H = 128, S = 10;
  // stride 264 bf16 = 528 B = 132 banks -> row-to-row bank shift of 4; the
  // 16-lane m-sweep of a b128 frag read lands 2-way max (free per m136).
  constexpr int STR = K + 8;

  __shared__ unsigned short Clds[B_TILE * STR];  // combined rows, bf16  (33.8 KB)
  __shared__ unsigned short Wt[H * STR];         // W^T [h][k], bf16     (67.6 KB)

  const int t = threadIdx.x;
  const int block0 = blockIdx.x * B_TILE;

  // ---- Phase 0: stage W (fp32 [K][H] row-major) -> Wt[h][k] bf16 ----
  {
    const float4* W4 = (const float4*)W;
#pragma unroll
    for (int i = 0; i < (K * H / 4) / THREADS; ++i) {   // 16 iters
      int f4i = i * THREADS + t;                        // 0..8191
      float4 v = W4[f4i];
      int flat = f4i << 2;
      int k = flat >> 7;          // /H
      int h = flat & (H - 1);
      Wt[(h + 0) * STR + k] = f2bf(v.x);
      Wt[(h + 1) * STR + k] = f2bf(v.y);
      Wt[(h + 2) * STR + k] = f2bf(v.z);
      Wt[(h + 3) * STR + k] = f2bf(v.w);
    }
  }

  // ---- Phase 1: gather self + mean(neigh) -> Clds rows (bf16) ----
  {
    const int r   = t >> 3;   // row within tile, 0..63
    const int sub = t & 7;    // 8 threads cooperate per row
    const int b   = block0 + r;
    ushort4* cself = (ushort4*)&Clds[r * STR];
    ushort4* cmean = (ushort4*)&Clds[r * STR + D];
    if (b < B) {
      const float4* fbase = (const float4*)feat;        // feature row = 32 float4
      const long srow = (long)nodes[b] * (D / 4);
      float4 sf[4];
#pragma unroll
      for (int j = 0; j < 4; ++j) sf[j] = fbase[srow + j * 8 + sub];
      float ax[4], ay[4], az[4], aw[4];
#pragma unroll
      for (int j = 0; j < 4; ++j) { ax[j] = 0.f; ay[j] = 0.f; az[j] = 0.f; aw[j] = 0.f; }
#pragma unroll
      for (int s = 0; s < S; ++s) {
        const long nrow = (long)neigh[b * S + s] * (D / 4);
#pragma unroll
        for (int j = 0; j < 4; ++j) {
          float4 v = fbase[nrow + j * 8 + sub];
          ax[j] += v.x; ay[j] += v.y; az[j] += v.z; aw[j] += v.w;
        }
      }
#pragma unroll
      for (int j = 0; j < 4; ++j) {
        int q = j * 8 + sub;       // float4 slot within the 128-wide half
        ushort4 sv, mv;
        sv.x = f2bf(sf[j].x); sv.y = f2bf(sf[j].y);
        sv.z = f2bf(sf[j].z); sv.w = f2bf(sf[j].w);
        mv.x = f2bf(ax[j] * 0.1f); mv.y = f2bf(ay[j] * 0.1f);
        mv.z = f2bf(az[j] * 0.1f); mv.w = f2bf(aw[j] * 0.1f);
        cself[q] = sv;
        cmean[q] = mv;
      }
    } else {
      ushort4 z; z.x = z.y = z.z = z.w = 0;
#pragma unroll
      for (int j = 0; j < 4; ++j) {
        int q = j * 8 + sub;
        cself[q] = z;
        cmean[q] = z;
      }
    }
  }
  __syncthreads();

  // ---- Phase 2: MFMA 64x128 = Clds[64x256] @ W[256x128], relu, store ----
  const int lane = t & 63;
  const int wave = t >> 6;            // 0..7
  const int m    = lane & 15;
  const int quad = lane >> 4;
  const int rbase = (wave & 1) * 32;  // row-tile pair base (rows)
  const int cbase = (wave >> 1) * 32; // col-tile pair base (cols)

  f32x4 acc00 = {0.f, 0.f, 0.f, 0.f};
  f32x4 acc01 = {0.f, 0.f, 0.f, 0.f};
  f32x4 acc10 = {0.f, 0.f, 0.f, 0.f};
  f32x4 acc11 = {0.f, 0.f, 0.f, 0.f};

#pragma unroll
  for (int ks = 0; ks < K / 32; ++ks) {
    const int koff = ks * 32 + quad * 8;
    // A-frag: A[m=lane&15][k=quad*8+j]  (verified m120)
    bf16x8 a0 = *(const bf16x8*)&Clds[(rbase      + m) * STR + koff];
    bf16x8 a1 = *(const bf16x8*)&Clds[(rbase + 16 + m) * STR + koff];
    // B-frag: B^T row layout -> Wt[n=lane&15][k=quad*8+j]
    bf16x8 b0 = *(const bf16x8*)&Wt[(cbase      + m) * STR + koff];
    bf16x8 b1 = *(const bf16x8*)&Wt[(cbase + 16 + m) * STR + koff];
    acc00 = __builtin_amdgcn_mfma_f32_16x16x32_bf16(a0, b0, acc00, 0, 0, 0);
    acc01 = __builtin_amdgcn_mfma_f32_16x16x32_bf16(a0, b1, acc01, 0, 0, 0);
    acc10 = __builtin_amdgcn_mfma_f32_16x16x32_bf16(a1, b0, acc10, 0, 0, 0);
    acc11 = __builtin_amdgcn_mfma_f32_16x16x32_bf16(a1, b1, acc11, 0, 0, 0);
  }

  // C/D layout: col = lane&15, row = quad*4 + reg  (verified m89/m91)
#pragma unroll
  for (int reg = 0; reg < 4; ++reg) {
    const int row0 = rbase + quad * 4 + reg;       // tile rt=0
    const int row1 = rbase + 16 + quad * 4 + reg;  // tile rt=1
    const int gb0 = block0 + row0;
    const int gb1 = block0 + row1;
    if (gb0 < B) {
      out[(size_t)gb0 * H + cbase      + m] = fmaxf(acc00[reg], 0.0f);
      out[(size_t)gb0 * H + cbase + 16 + m] = fmaxf(acc01[reg], 0.0f);
    }
    if (gb1 < B) {
      out[(size_t)gb1 * H + cbase      + m] = fmaxf(acc10[reg], 0.0f);
      out[(size_t)gb1 * H + cbase + 16 + m] = fmaxf(acc11[reg], 0.0f);
    }
  }
}

extern "C" void kernel_launch(void* const* d_in, const int* in_sizes, int n_in,
                              void* d_out, int out_size, void* d_ws, size_t ws_size,
                              hipStream_t stream) {
  const int*   nodes = (const int*)d_in[0];
  const int*   neigh = (const int*)d_in[1];
  const float* feat  = (const float*)d_in[2];
  const float* W     = (const float*)d_in[3];
  float*       out   = (float*)d_out;
  const int B = in_sizes[0];          // 50000
  const int grid = (B + B_TILE - 1) / B_TILE;   // 782
  sage_fused<<<grid, THREADS, 0, stream>>>(nodes, neigh, feat, W, out, B);
}

// Round 3
// 142.109 us; speedup vs baseline: 1.0536x; 1.0536x over previous
//
#include <hip/hip_runtime.h>

// GraphSAGE fused layer: out[B,128] = relu(concat(feat[nodes], mean_s feat[neigh])[B,256] @ W[256,128])
// B=50000, S=10, D=128, H=128. fp32 in/out; bf16 MFMA (threshold allows bf16).
//
// R3: split design. (1) prep: W -> bf16 W^T in ws (once, conflict-free).
// (2) gather: LDS-free, launch_bounds(256,6) ~24 waves/CU for the dominant
// random-gather phase; writes combined bf16 [B,256] to ws (or aliases d_out).
// (3) gemm: 64-row tiles, 8 waves x (64 rows x 16 cols), bfrag in VGPRs.
// R2's bug (waves covered only cols 0..63) fixed: cbase = wave*16 covers 128.

typedef __attribute__((ext_vector_type(8))) short bf16x8;   // 8 bf16 (4 VGPRs)
typedef __attribute__((ext_vector_type(4))) float f32x4;    // MFMA C/D frag

__device__ __forceinline__ unsigned short f2bf(float x) {
  unsigned int u = __float_as_uint(x);
  u += 0x7fffu + ((u >> 16) & 1u);
  return (unsigned short)(u >> 16);
}

// W [K=256][H=128] fp32 row-major -> Wt [H=128][K=256] bf16 (global, once).
__global__ void sage_prep_wt(const float* __restrict__ W,
                             unsigned short* __restrict__ Wt) {
  int tid = blockIdx.x * blockDim.x + threadIdx.x;   // 0..8191 (float4 units)
  const float4* W4 = (const float4*)W;
  float4 v = W4[tid];
  int flat = tid << 2;
  int k = flat >> 7;          // / H
  int h = flat & 127;         // % H
  Wt[(h + 0) * 256 + k] = f2bf(v.x);
  Wt[(h + 1) * 256 + k] = f2bf(v.y);
  Wt[(h + 2) * 256 + k] = f2bf(v.z);
  Wt[(h + 3) * 256 + k] = f2bf(v.w);
}

// Gather: comb[b][0:128]=feat[nodes[b]], comb[b][128:256]=mean_s feat[neigh[b][s]], bf16.
// 16 threads/row, 2 float4 each; no LDS -> occupancy limited only by VGPRs.
__global__ __launch_bounds__(256, 6)
void sage_gather(const int* __restrict__ nodes,
                 const int* __restrict__ neigh,
                 const float* __restrict__ feat,
                 unsigned short* __restrict__ comb,
                 int B)
{
  const int t   = threadIdx.x;
  const int r   = t >> 4;           // 0..15
  const int sub = t & 15;
  const int b   = blockIdx.x * 16 + r;
  if (b >= B) return;

  const float4* fbase = (const float4*)feat;   // feature row = 32 float4
  const long srow = (long)nodes[b] * 32;
  float4 s0 = fbase[srow + sub];
  float4 s1 = fbase[srow + 16 + sub];

  float m0x=0.f,m0y=0.f,m0z=0.f,m0w=0.f, m1x=0.f,m1y=0.f,m1z=0.f,m1w=0.f;
#pragma unroll
  for (int s = 0; s < 10; ++s) {
    const long nrow = (long)neigh[b * 10 + s] * 32;
    float4 v0 = fbase[nrow + sub];
    float4 v1 = fbase[nrow + 16 + sub];
    m0x += v0.x; m0y += v0.y; m0z += v0.z; m0w += v0.w;
    m1x += v1.x; m1y += v1.y; m1z += v1.z; m1w += v1.w;
  }

  ushort4* crow = (ushort4*)(comb + (size_t)b * 256);   // 64 ushort4 per row
  ushort4 a, c;
  a.x = f2bf(s0.x); a.y = f2bf(s0.y); a.z = f2bf(s0.z); a.w = f2bf(s0.w);
  crow[sub] = a;
  a.x = f2bf(s1.x); a.y = f2bf(s1.y); a.z = f2bf(s1.z); a.w = f2bf(s1.w);
  crow[16 + sub] = a;
  c.x = f2bf(m0x * 0.1f); c.y = f2bf(m0y * 0.1f);
  c.z = f2bf(m0z * 0.1f); c.w = f2bf(m0w * 0.1f);
  crow[32 + sub] = c;
  c.x = f2bf(m1x * 0.1f); c.y = f2bf(m1y * 0.1f);
  c.z = f2bf(m1z * 0.1f); c.w = f2bf(m1w * 0.1f);
  crow[48 + sub] = c;
}

// GEMM: out[64-tile][128] = relu(comb[64x256] @ W[256x128]).
// Each of 8 waves: 64 rows x 16 cols (cbase = wave*16 -> full 128 cols).
__global__ __launch_bounds__(512, 4)
void sage_gemm(const unsigned short* __restrict__ comb,
               const unsigned short* __restrict__ Wt,
               float* __restrict__ out,
               int B)
{
  constexpr int K = 256, H = 128, STR = K + 8;   // pad: 528 B rows, bank shift 4
  __shared__ unsigned short Clds[64 * STR];      // 33.8 KB

  const int t = threadIdx.x;
  const int block0 = blockIdx.x * 64;

  // Stage 64 rows x 512 B from comb into padded LDS (coalesced uint4).
  const uint4* c4 = (const uint4*)comb;
#pragma unroll
  for (int p = 0; p < 4; ++p) {
    int c = p * 512 + t;            // 0..2047 (16B chunks; 32 per row)
    int row = c >> 5;
    int off = (c & 31) * 8;         // element offset within row
    int gb = block0 + row;
    uint4 v;
    if (gb < B) v = c4[(size_t)gb * 32 + (c & 31)];
    else { v.x = v.y = v.z = v.w = 0u; }
    *(uint4*)&Clds[row * STR + off] = v;
  }
  __syncthreads();

  const int lane = t & 63;
  const int wave = t >> 6;          // 0..7
  const int m    = lane & 15;
  const int quad = lane >> 4;
  const int cbase = wave * 16;      // 8 waves x 16 = 128 cols

  // B-fragments in registers: Wt row (cbase+m), 16 B contiguous per ks.
  bf16x8 bfrag[8];
#pragma unroll
  for (int ks = 0; ks < 8; ++ks)
    bfrag[ks] = *(const bf16x8*)&Wt[(cbase + m) * K + ks * 32 + quad * 8];

  f32x4 acc[4];
#pragma unroll
  for (int rt = 0; rt < 4; ++rt) acc[rt] = (f32x4){0.f, 0.f, 0.f, 0.f};

#pragma unroll
  for (int ks = 0; ks < 8; ++ks) {
    const int koff = ks * 32 + quad * 8;
#pragma unroll
    for (int rt = 0; rt < 4; ++rt) {
      bf16x8 a = *(const bf16x8*)&Clds[(rt * 16 + m) * STR + koff];
      acc[rt] = __builtin_amdgcn_mfma_f32_16x16x32_bf16(a, bfrag[ks], acc[rt], 0, 0, 0);
    }
  }

  // C/D layout: col = lane&15, row = quad*4 + reg (verified m89/m91)
#pragma unroll
  for (int rt = 0; rt < 4; ++rt) {
#pragma unroll
    for (int reg = 0; reg < 4; ++reg) {
      const int row = rt * 16 + quad * 4 + reg;
      const int gb = block0 + row;
      if (gb < B) out[(size_t)gb * H + cbase + m] = fmaxf(acc[rt][reg], 0.0f);
    }
  }
}

extern "C" void kernel_launch(void* const* d_in, const int* in_sizes, int n_in,
                              void* d_out, int out_size, void* d_ws, size_t ws_size,
                              hipStream_t stream) {
  const int*   nodes = (const int*)d_in[0];
  const int*   neigh = (const int*)d_in[1];
  const float* feat  = (const float*)d_in[2];
  const float* W     = (const float*)d_in[3];
  float*       out   = (float*)d_out;
  const int B = in_sizes[0];                       // 50000

  unsigned short* Wt = (unsigned short*)d_ws;      // 64 KB
  const size_t need = 65536 + (size_t)B * 256 * 2; // Wt + combined
  // combined: ws if it fits, else alias d_out (same 512 B/row footprint;
  // gemm stages a tile's rows into LDS before overwriting them -> safe).
  unsigned short* comb = (ws_size >= need)
                           ? (unsigned short*)((char*)d_ws + 65536)
                           : (unsigned short*)d_out;

  sage_prep_wt<<<32, 256, 0, stream>>>(W, Wt);
  sage_gather<<<(B + 15) / 16, 256, 0, stream>>>(nodes, neigh, feat, comb, B);
  sage_gemm<<<(B + 63) / 64, 512, 0, stream>>>(comb, Wt, out, B);
}

// Round 4
// 131.731 us; speedup vs baseline: 1.1366x; 1.0788x over previous
//
#include <hip/hip_runtime.h>

// GraphSAGE fused layer: out[B,128] = relu(concat(feat[nodes], mean_s feat[neigh])[B,256] @ W[256,128])
// B=50000, S=10, D=128, H=128. fp32 in/out; bf16 MFMA (threshold allows bf16).
//
// R4: (1) prep_feat converts the 51.2 MB fp32 feature table to a 25.6 MB bf16
// table in ws -> random gather reads halve and become L2/L3-resident.
// (2) gather+GEMM re-fused (no comb round-trip); W^T stays in VGPRs, LDS is a
// single 32 KB tile with 16B-chunk XOR swizzle (phys = j ^ (row&7)) -> both
// gather writes and MFMA A-frag ds_read_b128 are at the free 2-way minimum.

typedef __attribute__((ext_vector_type(8))) short bf16x8;   // 8 bf16 (4 VGPRs)
typedef __attribute__((ext_vector_type(4))) float f32x4;    // MFMA C/D frag

__device__ __forceinline__ unsigned short f2bf(float x) {
  unsigned int u = __float_as_uint(x);
  u += 0x7fffu + ((u >> 16) & 1u);
  return (unsigned short)(u >> 16);
}
__device__ __forceinline__ unsigned int pack2bf(float lo, float hi) {
  return (unsigned int)f2bf(lo) | ((unsigned int)f2bf(hi) << 16);
}
__device__ __forceinline__ float bflo(unsigned int u) { return __uint_as_float(u << 16); }
__device__ __forceinline__ float bfhi(unsigned int u) { return __uint_as_float(u & 0xffff0000u); }

// W [K=256][H=128] fp32 row-major -> Wt [H=128][K=256] bf16 (once).
__global__ void sage_prep_wt(const float* __restrict__ W,
                             unsigned short* __restrict__ Wt) {
  int tid = blockIdx.x * blockDim.x + threadIdx.x;   // 0..8191 (float4 units)
  float4 v = ((const float4*)W)[tid];
  int flat = tid << 2;
  int k = flat >> 7;          // / H
  int h = flat & 127;         // % H
  Wt[(h + 0) * 256 + k] = f2bf(v.x);
  Wt[(h + 1) * 256 + k] = f2bf(v.y);
  Wt[(h + 2) * 256 + k] = f2bf(v.z);
  Wt[(h + 3) * 256 + k] = f2bf(v.w);
}

// feat fp32 [N,128] -> bf16 table (packed pairs), streaming.
__global__ void sage_prep_feat(const float* __restrict__ feat,
                               unsigned int* __restrict__ fb, int n4) {
  int tid = blockIdx.x * blockDim.x + threadIdx.x;   // float4 units
  if (tid >= n4) return;
  float4 v = ((const float4*)feat)[tid];
  uint2 o; o.x = pack2bf(v.x, v.y); o.y = pack2bf(v.z, v.w);
  ((uint2*)fb)[tid] = o;
}

// Fused gather + GEMM. BT=true reads the bf16 table; BT=false falls back to fp32 feat.
template <bool BT>
__global__ __launch_bounds__(512, 4)
void sage_fused2(const int* __restrict__ nodes,
                 const int* __restrict__ neigh,
                 const float* __restrict__ featf,
                 const uint4* __restrict__ featb,
                 const unsigned short* __restrict__ Wt,
                 float* __restrict__ out, int B)
{
  constexpr int K = 256, H = 128, S = 10;
  // 64 rows x 256 bf16, no pad; 16B chunk j of row r stored at phys chunk j^(r&7).
  __shared__ unsigned short Clds[64 * 256];   // 32 KB

  const int t = threadIdx.x;
  const int block0 = blockIdx.x * 64;

  // ---- Phase 1: gather self + mean(neigh) -> swizzled LDS tile ----
  {
    const int r   = t >> 3;     // 0..63
    const int sub = t & 7;      // 8 threads/row
    const int b   = block0 + r;
    const int key = r & 7;
    uint4* c0 = (uint4*)&Clds[r * 256 + ((sub     ) ^ key) * 8];
    uint4* c1 = (uint4*)&Clds[r * 256 + ((sub +  8) ^ key) * 8];
    uint4* c2 = (uint4*)&Clds[r * 256 + ((sub + 16) ^ key) * 8];
    uint4* c3 = (uint4*)&Clds[r * 256 + ((sub + 24) ^ key) * 8];
    if (b < B) {
      float a0[8], a1[8];
#pragma unroll
      for (int i = 0; i < 8; ++i) { a0[i] = 0.f; a1[i] = 0.f; }
      uint4 s0, s1;
      if (BT) {
        const long srow = (long)nodes[b] * 16;      // row = 16 uint4
        s0 = featb[srow + sub];
        s1 = featb[srow + 8 + sub];
#pragma unroll
        for (int s = 0; s < S; ++s) {
          const long nrow = (long)neigh[b * S + s] * 16;
          uint4 v0 = featb[nrow + sub];
          uint4 v1 = featb[nrow + 8 + sub];
          a0[0] += bflo(v0.x); a0[1] += bfhi(v0.x); a0[2] += bflo(v0.y); a0[3] += bfhi(v0.y);
          a0[4] += bflo(v0.z); a0[5] += bfhi(v0.z); a0[6] += bflo(v0.w); a0[7] += bfhi(v0.w);
          a1[0] += bflo(v1.x); a1[1] += bfhi(v1.x); a1[2] += bflo(v1.y); a1[3] += bfhi(v1.y);
          a1[4] += bflo(v1.z); a1[5] += bfhi(v1.z); a1[6] += bflo(v1.w); a1[7] += bfhi(v1.w);
        }
      } else {
        const float4* f4 = (const float4*)featf;    // row = 32 float4
        const long srow = (long)nodes[b] * 32;
        float4 p, q;
        p = f4[srow + 2 * sub]; q = f4[srow + 2 * sub + 1];
        s0.x = pack2bf(p.x, p.y); s0.y = pack2bf(p.z, p.w);
        s0.z = pack2bf(q.x, q.y); s0.w = pack2bf(q.z, q.w);
        p = f4[srow + 16 + 2 * sub]; q = f4[srow + 17 + 2 * sub];
        s1.x = pack2bf(p.x, p.y); s1.y = pack2bf(p.z, p.w);
        s1.z = pack2bf(q.x, q.y); s1.w = pack2bf(q.z, q.w);
#pragma unroll
        for (int s = 0; s < S; ++s) {
          const long nrow = (long)neigh[b * S + s] * 32;
          float4 v;
          v = f4[nrow + 2 * sub];      a0[0] += v.x; a0[1] += v.y; a0[2] += v.z; a0[3] += v.w;
          v = f4[nrow + 2 * sub + 1];  a0[4] += v.x; a0[5] += v.y; a0[6] += v.z; a0[7] += v.w;
          v = f4[nrow + 16 + 2 * sub]; a1[0] += v.x; a1[1] += v.y; a1[2] += v.z; a1[3] += v.w;
          v = f4[nrow + 17 + 2 * sub]; a1[4] += v.x; a1[5] += v.y; a1[6] += v.z; a1[7] += v.w;
        }
      }
      *c0 = s0;
      *c1 = s1;
      uint4 m0, m1;
      m0.x = pack2bf(a0[0] * 0.1f, a0[1] * 0.1f); m0.y = pack2bf(a0[2] * 0.1f, a0[3] * 0.1f);
      m0.z = pack2bf(a0[4] * 0.1f, a0[5] * 0.1f); m0.w = pack2bf(a0[6] * 0.1f, a0[7] * 0.1f);
      m1.x = pack2bf(a1[0] * 0.1f, a1[1] * 0.1f); m1.y = pack2bf(a1[2] * 0.1f, a1[3] * 0.1f);
      m1.z = pack2bf(a1[4] * 0.1f, a1[5] * 0.1f); m1.w = pack2bf(a1[6] * 0.1f, a1[7] * 0.1f);
      *c2 = m0;
      *c3 = m1;
    } else {
      uint4 z; z.x = z.y = z.z = z.w = 0u;
      *c0 = z; *c1 = z; *c2 = z; *c3 = z;
    }
  }
  __syncthreads();

  // ---- Phase 2: 8 waves x (64 rows x 16 cols) MFMA ----
  const int lane = t & 63;
  const int wave = t >> 6;
  const int m    = lane & 15;
  const int quad = lane >> 4;
  const int cbase = wave * 16;      // 8 x 16 = 128 cols
  const int mk   = m & 7;           // swizzle key of row rt*16+m

  bf16x8 bfrag[8];
#pragma unroll
  for (int ks = 0; ks < 8; ++ks)
    bfrag[ks] = *(const bf16x8*)&Wt[(cbase + m) * K + ks * 32 + quad * 8];

  f32x4 acc[4];
#pragma unroll
  for (int rt = 0; rt < 4; ++rt) acc[rt] = (f32x4){0.f, 0.f, 0.f, 0.f};

#pragma unroll
  for (int ks = 0; ks < 8; ++ks) {
    const int pj = ((ks * 4 + quad) ^ mk) * 8;    // phys chunk -> element offset
#pragma unroll
    for (int rt = 0; rt < 4; ++rt) {
      bf16x8 a = *(const bf16x8*)&Clds[(rt * 16 + m) * 256 + pj];
      acc[rt] = __builtin_amdgcn_mfma_f32_16x16x32_bf16(a, bfrag[ks], acc[rt], 0, 0, 0);
    }
  }

  // C/D layout: col = lane&15, row = quad*4 + reg (verified m89/m91)
#pragma unroll
  for (int rt = 0; rt < 4; ++rt) {
#pragma unroll
    for (int reg = 0; reg < 4; ++reg) {
      const int row = rt * 16 + quad * 4 + reg;
      const int gb = block0 + row;
      if (gb < B) out[(size_t)gb * H + cbase + m] = fmaxf(acc[rt][reg], 0.0f);
    }
  }
}

extern "C" void kernel_launch(void* const* d_in, const int* in_sizes, int n_in,
                              void* d_out, int out_size, void* d_ws, size_t ws_size,
                              hipStream_t stream) {
  const int*   nodes = (const int*)d_in[0];
  const int*   neigh = (const int*)d_in[1];
  const float* feat  = (const float*)d_in[2];
  const float* W     = (const float*)d_in[3];
  float*       out   = (float*)d_out;
  const int B  = in_sizes[0];                 // 50000
  const int nf = in_sizes[2];                 // N_NODES*128
  const int nf4 = nf / 4;

  unsigned short* Wt = (unsigned short*)d_ws;             // 64 KB
  const size_t need = 65536 + (size_t)nf * 2;             // Wt + bf16 table

  sage_prep_wt<<<32, 256, 0, stream>>>(W, Wt);
  const int grid = (B + 63) / 64;                         // 782

  if (ws_size >= need) {
    unsigned int* fb = (unsigned int*)((char*)d_ws + 65536);
    sage_prep_feat<<<(nf4 + 255) / 256, 256, 0, stream>>>(feat, fb, nf4);
    sage_fused2<true><<<grid, 512, 0, stream>>>(nodes, neigh, nullptr,
                                                (const uint4*)fb, Wt, out, B);
  } else {
    sage_fused2<false><<<grid, 512, 0, stream>>>(nodes, neigh, feat,
                                                 nullptr, Wt, out, B);
  }
}

// Round 5
// 131.302 us; speedup vs baseline: 1.1403x; 1.0033x over previous
//
#include <hip/hip_runtime.h>

// GraphSAGE fused layer: out[B,128] = relu(concat(feat[nodes], mean_s feat[neigh])[B,256] @ W[256,128])
// B=50000, S=10, D=128, H=128. fp32 in/out; bf16 MFMA (threshold allows bf16).
//
// R5: fused kernel occupancy 2 -> 3 blocks/CU (__launch_bounds__(512,6), VGPR
// cap 85). sched_barrier(0) at the phase boundary keeps the 32-VGPR W^T
// fragments out of the gather phase's register lifetime. Structure otherwise
// = R4: bf16 feature table in ws (25.6 MB, L2/L3-resident random gather),
// XOR-swizzled 32 KB LDS tile, W^T fragments in VGPRs.

typedef __attribute__((ext_vector_type(8))) short bf16x8;   // 8 bf16 (4 VGPRs)
typedef __attribute__((ext_vector_type(4))) float f32x4;    // MFMA C/D frag

__device__ __forceinline__ unsigned short f2bf(float x) {
  unsigned int u = __float_as_uint(x);
  u += 0x7fffu + ((u >> 16) & 1u);
  return (unsigned short)(u >> 16);
}
__device__ __forceinline__ unsigned int pack2bf(float lo, float hi) {
  return (unsigned int)f2bf(lo) | ((unsigned int)f2bf(hi) << 16);
}
__device__ __forceinline__ float bflo(unsigned int u) { return __uint_as_float(u << 16); }
__device__ __forceinline__ float bfhi(unsigned int u) { return __uint_as_float(u & 0xffff0000u); }

// W [K=256][H=128] fp32 row-major -> Wt [H=128][K=256] bf16 (once).
__global__ void sage_prep_wt(const float* __restrict__ W,
                             unsigned short* __restrict__ Wt) {
  int tid = blockIdx.x * blockDim.x + threadIdx.x;   // 0..8191 (float4 units)
  float4 v = ((const float4*)W)[tid];
  int flat = tid << 2;
  int k = flat >> 7;          // / H
  int h = flat & 127;         // % H
  Wt[(h + 0) * 256 + k] = f2bf(v.x);
  Wt[(h + 1) * 256 + k] = f2bf(v.y);
  Wt[(h + 2) * 256 + k] = f2bf(v.z);
  Wt[(h + 3) * 256 + k] = f2bf(v.w);
}

// feat fp32 [N,128] -> bf16 table (packed pairs), streaming.
__global__ void sage_prep_feat(const float* __restrict__ feat,
                               unsigned int* __restrict__ fb, int n4) {
  int tid = blockIdx.x * blockDim.x + threadIdx.x;   // float4 units
  if (tid >= n4) return;
  float4 v = ((const float4*)feat)[tid];
  uint2 o; o.x = pack2bf(v.x, v.y); o.y = pack2bf(v.z, v.w);
  ((uint2*)fb)[tid] = o;
}

// Fused gather + GEMM. BT=true reads the bf16 table; BT=false reads fp32 feat.
template <bool BT>
__global__ __launch_bounds__(512, 6)
void sage_fused2(const int* __restrict__ nodes,
                 const int* __restrict__ neigh,
                 const float* __restrict__ featf,
                 const uint4* __restrict__ featb,
                 const unsigned short* __restrict__ Wt,
                 float* __restrict__ out, int B)
{
  constexpr int K = 256, H = 128, S = 10;
  // 64 rows x 256 bf16, no pad; 16B chunk j of row r stored at phys chunk j^(r&7).
  __shared__ unsigned short Clds[64 * 256];   // 32 KB

  const int t = threadIdx.x;
  const int block0 = blockIdx.x * 64;

  // ---- Phase 1: gather self + mean(neigh) -> swizzled LDS tile ----
  {
    const int r   = t >> 3;     // 0..63
    const int sub = t & 7;      // 8 threads/row
    const int b   = block0 + r;
    const int key = r & 7;
    uint4* c0 = (uint4*)&Clds[r * 256 + ((sub     ) ^ key) * 8];
    uint4* c1 = (uint4*)&Clds[r * 256 + ((sub +  8) ^ key) * 8];
    uint4* c2 = (uint4*)&Clds[r * 256 + ((sub + 16) ^ key) * 8];
    uint4* c3 = (uint4*)&Clds[r * 256 + ((sub + 24) ^ key) * 8];
    if (b < B) {
      float a0[8], a1[8];
#pragma unroll
      for (int i = 0; i < 8; ++i) { a0[i] = 0.f; a1[i] = 0.f; }
      uint4 s0, s1;
      if (BT) {
        const long srow = (long)nodes[b] * 16;      // row = 16 uint4
        s0 = featb[srow + sub];
        s1 = featb[srow + 8 + sub];
#pragma unroll
        for (int s = 0; s < S; ++s) {
          const long nrow = (long)neigh[b * S + s] * 16;
          uint4 v0 = featb[nrow + sub];
          uint4 v1 = featb[nrow + 8 + sub];
          a0[0] += bflo(v0.x); a0[1] += bfhi(v0.x); a0[2] += bflo(v0.y); a0[3] += bfhi(v0.y);
          a0[4] += bflo(v0.z); a0[5] += bfhi(v0.z); a0[6] += bflo(v0.w); a0[7] += bfhi(v0.w);
          a1[0] += bflo(v1.x); a1[1] += bfhi(v1.x); a1[2] += bflo(v1.y); a1[3] += bfhi(v1.y);
          a1[4] += bflo(v1.z); a1[5] += bfhi(v1.z); a1[6] += bflo(v1.w); a1[7] += bfhi(v1.w);
        }
      } else {
        const float4* f4 = (const float4*)featf;    // row = 32 float4
        const long srow = (long)nodes[b] * 32;
        float4 p, q;
        p = f4[srow + 2 * sub]; q = f4[srow + 2 * sub + 1];
        s0.x = pack2bf(p.x, p.y); s0.y = pack2bf(p.z, p.w);
        s0.z = pack2bf(q.x, q.y); s0.w = pack2bf(q.z, q.w);
        p = f4[srow + 16 + 2 * sub]; q = f4[srow + 17 + 2 * sub];
        s1.x = pack2bf(p.x, p.y); s1.y = pack2bf(p.z, p.w);
        s1.z = pack2bf(q.x, q.y); s1.w = pack2bf(q.z, q.w);
#pragma unroll
        for (int s = 0; s < S; ++s) {
          const long nrow = (long)neigh[b * S + s] * 32;
          float4 v;
          v = f4[nrow + 2 * sub];      a0[0] += v.x; a0[1] += v.y; a0[2] += v.z; a0[3] += v.w;
          v = f4[nrow + 2 * sub + 1];  a0[4] += v.x; a0[5] += v.y; a0[6] += v.z; a0[7] += v.w;
          v = f4[nrow + 16 + 2 * sub]; a1[0] += v.x; a1[1] += v.y; a1[2] += v.z; a1[3] += v.w;
          v = f4[nrow + 17 + 2 * sub]; a1[4] += v.x; a1[5] += v.y; a1[6] += v.z; a1[7] += v.w;
        }
      }
      *c0 = s0;
      *c1 = s1;
      uint4 m0, m1;
      m0.x = pack2bf(a0[0] * 0.1f, a0[1] * 0.1f); m0.y = pack2bf(a0[2] * 0.1f, a0[3] * 0.1f);
      m0.z = pack2bf(a0[4] * 0.1f, a0[5] * 0.1f); m0.w = pack2bf(a0[6] * 0.1f, a0[7] * 0.1f);
      m1.x = pack2bf(a1[0] * 0.1f, a1[1] * 0.1f); m1.y = pack2bf(a1[2] * 0.1f, a1[3] * 0.1f);
      m1.z = pack2bf(a1[4] * 0.1f, a1[5] * 0.1f); m1.w = pack2bf(a1[6] * 0.1f, a1[7] * 0.1f);
      *c2 = m0;
      *c3 = m1;
    } else {
      uint4 z; z.x = z.y = z.z = z.w = 0u;
      *c0 = z; *c1 = z; *c2 = z; *c3 = z;
    }
  }
  __syncthreads();
  // Keep phase-2 Wt loads out of phase 1's register lifetime (occupancy cap 85 VGPR).
  __builtin_amdgcn_sched_barrier(0);

  // ---- Phase 2: 8 waves x (64 rows x 16 cols) MFMA ----
  const int lane = t & 63;
  const int wave = t >> 6;
  const int m    = lane & 15;
  const int quad = lane >> 4;
  const int cbase = wave * 16;      // 8 x 16 = 128 cols
  const int mk   = m & 7;           // swizzle key of row rt*16+m

  bf16x8 bfrag[8];
#pragma unroll
  for (int ks = 0; ks < 8; ++ks)
    bfrag[ks] = *(const bf16x8*)&Wt[(cbase + m) * K + ks * 32 + quad * 8];

  f32x4 acc[4];
#pragma unroll
  for (int rt = 0; rt < 4; ++rt) acc[rt] = (f32x4){0.f, 0.f, 0.f, 0.f};

#pragma unroll
  for (int ks = 0; ks < 8; ++ks) {
    const int pj = ((ks * 4 + quad) ^ mk) * 8;    // phys chunk -> element offset
#pragma unroll
    for (int rt = 0; rt < 4; ++rt) {
      bf16x8 a = *(const bf16x8*)&Clds[(rt * 16 + m) * 256 + pj];
      acc[rt] = __builtin_amdgcn_mfma_f32_16x16x32_bf16(a, bfrag[ks], acc[rt], 0, 0, 0);
    }
  }

  // C/D layout: col = lane&15, row = quad*4 + reg (verified m89/m91)
#pragma unroll
  for (int rt = 0; rt < 4; ++rt) {
#pragma unroll
    for (int reg = 0; reg < 4; ++reg) {
      const int row = rt * 16 + quad * 4 + reg;
      const int gb = block0 + row;
      if (gb < B) out[(size_t)gb * H + cbase + m] = fmaxf(acc[rt][reg], 0.0f);
    }
  }
}

extern "C" void kernel_launch(void* const* d_in, const int* in_sizes, int n_in,
                              void* d_out, int out_size, void* d_ws, size_t ws_size,
                              hipStream_t stream) {
  const int*   nodes = (const int*)d_in[0];
  const int*   neigh = (const int*)d_in[1];
  const float* feat  = (const float*)d_in[2];
  const float* W     = (const float*)d_in[3];
  float*       out   = (float*)d_out;
  const int B  = in_sizes[0];                 // 50000
  const int nf = in_sizes[2];                 // N_NODES*128
  const int nf4 = nf / 4;

  unsigned short* Wt = (unsigned short*)d_ws;             // 64 KB
  const size_t need = 65536 + (size_t)nf * 2;             // Wt + bf16 table

  sage_prep_wt<<<32, 256, 0, stream>>>(W, Wt);
  const int grid = (B + 63) / 64;                         // 782

  if (ws_size >= need) {
    unsigned int* fb = (unsigned int*)((char*)d_ws + 65536);
    sage_prep_feat<<<(nf4 + 255) / 256, 256, 0, stream>>>(feat, fb, nf4);
    sage_fused2<true><<<grid, 512, 0, stream>>>(nodes, neigh, nullptr,
                                                (const uint4*)fb, Wt, out, B);
  } else {
    sage_fused2<false><<<grid, 512, 0, stream>>>(nodes, neigh, feat,
                                                 nullptr, Wt, out, B);
  }
}

// Round 6
// 129.647 us; speedup vs baseline: 1.1548x; 1.0128x over previous
//
#include <hip/hip_runtime.h>

// GraphSAGE fused layer: out[B,128] = relu(concat(feat[nodes], mean_s feat[neigh])[B,256] @ W[256,128])
// B=50000, S=10, D=128, H=128. fp32 in/out; bf16 MFMA (threshold allows bf16).
//
// R6: prep_feat dropped (R4/R5 showed gather time tracks row count, not bytes
// -> the 12 us fp32->bf16 table pass bought nothing). Fused kernel gathers
// fp32 directly with R3's proven geometry: 16 threads/row, 2x256B float4
// segments per source row. Tile = 32 rows/block (512 thr), LDS 16.9 KB
// (stride 528 B = 4-bank row shift; MFMA A-frag ds_read_b128 at free 2-way).

typedef __attribute__((ext_vector_type(8))) short bf16x8;   // 8 bf16 (4 VGPRs)
typedef __attribute__((ext_vector_type(4))) float f32x4;    // MFMA C/D frag

__device__ __forceinline__ unsigned short f2bf(float x) {
  unsigned int u = __float_as_uint(x);
  u += 0x7fffu + ((u >> 16) & 1u);
  return (unsigned short)(u >> 16);
}

// W [K=256][H=128] fp32 row-major -> Wt [H=128][K=256] bf16 (once, to ws).
__global__ void sage_prep_wt(const float* __restrict__ W,
                             unsigned short* __restrict__ Wt) {
  int tid = blockIdx.x * blockDim.x + threadIdx.x;   // 0..8191 (float4 units)
  float4 v = ((const float4*)W)[tid];
  int flat = tid << 2;
  int k = flat >> 7;          // / H
  int h = flat & 127;         // % H
  Wt[(h + 0) * 256 + k] = f2bf(v.x);
  Wt[(h + 1) * 256 + k] = f2bf(v.y);
  Wt[(h + 2) * 256 + k] = f2bf(v.z);
  Wt[(h + 3) * 256 + k] = f2bf(v.w);
}

__global__ __launch_bounds__(512, 6)
void sage_fused3(const int* __restrict__ nodes,
                 const int* __restrict__ neigh,
                 const float* __restrict__ feat,
                 const unsigned short* __restrict__ Wt,
                 float* __restrict__ out, int B)
{
  constexpr int K = 256, H = 128, S = 10;
  constexpr int TILE = 32;
  constexpr int STR = K + 8;                   // 264 elems = 528 B rows
  __shared__ unsigned short Clds[TILE * STR];  // 16.9 KB

  const int t = threadIdx.x;
  const int block0 = blockIdx.x * TILE;

  // ---- Phase 1: gather self + mean(neigh) -> LDS tile (bf16) ----
  {
    const int r   = t >> 4;     // 0..31
    const int sub = t & 15;     // 16 threads/row (R3 geometry)
    const int b   = block0 + r;
    unsigned short* crow = &Clds[r * STR];
    if (b < B) {
      const float4* f4 = (const float4*)feat;   // feature row = 32 float4
      const long srow = (long)nodes[b] * 32;
      float4 s0 = f4[srow + sub];               // elems 4sub..4sub+3
      float4 s1 = f4[srow + 16 + sub];          // elems 64+4sub..

      float ax0=0.f, ay0=0.f, az0=0.f, aw0=0.f;
      float ax1=0.f, ay1=0.f, az1=0.f, aw1=0.f;
#pragma unroll
      for (int s = 0; s < S; ++s) {
        const long nrow = (long)neigh[b * S + s] * 32;
        float4 v0 = f4[nrow + sub];
        float4 v1 = f4[nrow + 16 + sub];
        ax0 += v0.x; ay0 += v0.y; az0 += v0.z; aw0 += v0.w;
        ax1 += v1.x; ay1 += v1.y; az1 += v1.z; aw1 += v1.w;
      }
      ushort4 o;
      o.x = f2bf(s0.x); o.y = f2bf(s0.y); o.z = f2bf(s0.z); o.w = f2bf(s0.w);
      *(ushort4*)&crow[4 * sub] = o;
      o.x = f2bf(s1.x); o.y = f2bf(s1.y); o.z = f2bf(s1.z); o.w = f2bf(s1.w);
      *(ushort4*)&crow[64 + 4 * sub] = o;
      o.x = f2bf(ax0 * 0.1f); o.y = f2bf(ay0 * 0.1f);
      o.z = f2bf(az0 * 0.1f); o.w = f2bf(aw0 * 0.1f);
      *(ushort4*)&crow[128 + 4 * sub] = o;
      o.x = f2bf(ax1 * 0.1f); o.y = f2bf(ay1 * 0.1f);
      o.z = f2bf(az1 * 0.1f); o.w = f2bf(aw1 * 0.1f);
      *(ushort4*)&crow[192 + 4 * sub] = o;
    } else {
      ushort4 z; z.x = z.y = z.z = z.w = 0;
      *(ushort4*)&crow[4 * sub] = z;
      *(ushort4*)&crow[64 + 4 * sub] = z;
      *(ushort4*)&crow[128 + 4 * sub] = z;
      *(ushort4*)&crow[192 + 4 * sub] = z;
    }
  }
  __syncthreads();
  __builtin_amdgcn_sched_barrier(0);   // keep Wt loads out of phase-1 lifetime

  // ---- Phase 2: 8 waves x (32 rows x 16 cols) MFMA ----
  const int lane = t & 63;
  const int wave = t >> 6;
  const int m    = lane & 15;
  const int quad = lane >> 4;
  const int cbase = wave * 16;      // 8 waves x 16 = 128 cols

  bf16x8 bfrag[8];
#pragma unroll
  for (int ks = 0; ks < 8; ++ks)
    bfrag[ks] = *(const bf16x8*)&Wt[(cbase + m) * K + ks * 32 + quad * 8];

  f32x4 acc0 = {0.f, 0.f, 0.f, 0.f};
  f32x4 acc1 = {0.f, 0.f, 0.f, 0.f};
#pragma unroll
  for (int ks = 0; ks < 8; ++ks) {
    const int koff = ks * 32 + quad * 8;
    bf16x8 a0 = *(const bf16x8*)&Clds[(m     ) * STR + koff];
    bf16x8 a1 = *(const bf16x8*)&Clds[(16 + m) * STR + koff];
    acc0 = __builtin_amdgcn_mfma_f32_16x16x32_bf16(a0, bfrag[ks], acc0, 0, 0, 0);
    acc1 = __builtin_amdgcn_mfma_f32_16x16x32_bf16(a1, bfrag[ks], acc1, 0, 0, 0);
  }

  // C/D layout: col = lane&15, row = quad*4 + reg (verified m89/m91)
#pragma unroll
  for (int reg = 0; reg < 4; ++reg) {
    const int row0 = quad * 4 + reg;
    const int gb0 = block0 + row0;
    const int gb1 = gb0 + 16;
    if (gb0 < B) out[(size_t)gb0 * H + cbase + m] = fmaxf(acc0[reg], 0.0f);
    if (gb1 < B) out[(size_t)gb1 * H + cbase + m] = fmaxf(acc1[reg], 0.0f);
  }
}

extern "C" void kernel_launch(void* const* d_in, const int* in_sizes, int n_in,
                              void* d_out, int out_size, void* d_ws, size_t ws_size,
                              hipStream_t stream) {
  const int*   nodes = (const int*)d_in[0];
  const int*   neigh = (const int*)d_in[1];
  const float* feat  = (const float*)d_in[2];
  const float* W     = (const float*)d_in[3];
  float*       out   = (float*)d_out;
  const int B = in_sizes[0];                       // 50000

  unsigned short* Wt = (unsigned short*)d_ws;      // 64 KB
  sage_prep_wt<<<32, 256, 0, stream>>>(W, Wt);
  const int grid = (B + 31) / 32;                  // 1563
  sage_fused3<<<grid, 512, 0, stream>>>(nodes, neigh, feat, Wt, out, B);
}